// Round 7
// baseline (637.679 us; speedup 1.0000x reference)
//
#include <hip/hip_runtime.h>
#include <cstdint>
#include <cstddef>

#define H2 1024
#define TT 512
#define NSTEPS 64
#define RBLK 32     // recurrence blocks
#define RTHR 512    // threads per block
#define TOTBLK 256
#define NTILES 2048u   // gemm tiles: 64 n * 8 e * 4 t (n-major -> pipeline order)
#define NOUT 512u      // out units: 64 n * 8 dblk(128)

using floatx4 = __attribute__((__ext_vector_type__(4))) float;
using half8   = __attribute__((__ext_vector_type__(8))) _Float16;
typedef unsigned long long u64;

__device__ __forceinline__ float tanh_fast(float x) {
  return 1.0f - 2.0f / (__expf(2.0f * x) + 1.0f);
}

// ---------------------------------------------------------------------------
// ONE cooperative kernel, NO pre-passes (the R4/R5 prepass HBM stream was the
// recurrence's contention source, and it is algorithmically unnecessary):
//   blocks [0,32):   64-step recurrence (data-as-flag, single poller wave,
//                    W pinned in VGPRs), then join GEMM queue, then out queue.
//   blocks [32,256): straight into the GEMM tile queue (no gate), then out.
// GEMM stages fp32 W and fp32 h DIRECTLY: load -> cvt fp16 in-reg -> ds_write.
//   A[128][32]: thread = half a W row (16 floats), 2x half8 LDS writes.
//   B[t][k]: thread = one k-row's 16 t values (coalesced 64B read), 16 scalar
//   LDS writes do the transpose in-LDS. Fragment reads/MFMA identical to the
//   proven R4 path (numerics bit-identical: same fp16 rounding).
// Pipeline: tiles are n-major; epilogue spins (1 thread) on norm2[n], which
// the recurrence publishes only AFTER all vbuf[n] words are LLC-visible, so
// vbuf can then be read with plain agent loads. GEMM self-throttles behind
// the recurrence; its K-loop cost is fully hidden.
// ---------------------------------------------------------------------------
__global__ __launch_bounds__(RTHR, 1) void fused_kernel(
    const float* __restrict__ W, const float* __restrict__ bias,
    const float* __restrict__ u0, float* __restrict__ vbuf,
    float* __restrict__ norm2, const float* __restrict__ h,
    float* __restrict__ scores, float* __restrict__ out,
    unsigned* __restrict__ ctrs) {
  __shared__ __align__(16) char smem[33792];
  int tid = threadIdx.x;
  unsigned* gemmq   = ctrs + 16;   // gemm tile queue
  unsigned* donecnt = ctrs + 32;   // per-n completed tiles (64)
  unsigned* outq    = ctrs + 96;   // out-unit queue

  if (blockIdx.x < RBLK) {
    // ------------------------- recurrence role ---------------------------
    float* ub = (float*)smem;              // [2][1024] double-buffered z
    float* bredn = (float*)(smem + 8192);  // [2] norm^2
    int w = tid >> 6, l = tid & 63;
    int r0 = blockIdx.x * RBLK + w * 4;

    floatx4 wreg[16];
    float blv[4];
#pragma unroll
    for (int p = 0; p < 4; ++p) {
      const float* wr = W + ((size_t)(r0 + p) << 10) + 4 * l;
#pragma unroll
      for (int j = 0; j < 4; ++j)
        wreg[p * 4 + j] = *(const floatx4*)(wr + 256 * j);
      blv[p] = bias[r0 + p];
    }
#pragma unroll
    for (int j = 0; j < 16; ++j) asm volatile("" : "+v"(wreg[j]));

    for (int i = 0; i < NSTEPS; ++i) {
      float* cb = ub + (i & 1) * 1024;
      float rs;
      if (i == 0) {
        if (w == 0) {
#pragma unroll
          for (int j = 0; j < 4; ++j) {
            floatx4 v = *((const floatx4*)u0 + l + 64 * j);
            *(floatx4*)(cb + 4 * l + 256 * j) = v;
          }
        }
        __syncthreads();
        rs = 1.0f;
      } else {
        if (w == 0) {
          const u64* src = (const u64*)(vbuf + ((size_t)(i - 1) << 10)) + l;
          u64 v[8];
          for (;;) {
            bool ok = true;
#pragma unroll
            for (int j = 0; j < 8; ++j) {
              v[j] = __hip_atomic_load(src + 64 * j, __ATOMIC_RELAXED,
                                       __HIP_MEMORY_SCOPE_AGENT);
              ok &= ((unsigned)(v[j] & 0xFFFFFFFFu) != 0xFFFFFFFFu) &
                    ((unsigned)(v[j] >> 32) != 0xFFFFFFFFu);
            }
            if (__all(ok)) break;
            __builtin_amdgcn_s_sleep(1);
          }
          float sq = 0.f;
#pragma unroll
          for (int j = 0; j < 8; ++j) {
            *(u64*)(cb + 2 * l + 128 * j) = v[j];
            float f0 =
                __builtin_bit_cast(float, (unsigned)(v[j] & 0xFFFFFFFFu));
            float f1 = __builtin_bit_cast(float, (unsigned)(v[j] >> 32));
            sq += f0 * f0 + f1 * f1;
          }
#pragma unroll
          for (int off = 1; off <= 32; off <<= 1)
            sq += __shfl_xor(sq, off, 64);
          if (l == 0) bredn[i & 1] = sq;
        }
        __syncthreads();
        float nrm = bredn[i & 1];
        rs = 1.0f / fmaxf(sqrtf(nrm), 1e-12f);
        if (blockIdx.x == 0 && tid == 64) {
          unsigned nb = __builtin_bit_cast(unsigned, nrm);
          __hip_atomic_store((unsigned*)(norm2 + (i - 1)), nb,
                             __ATOMIC_RELAXED, __HIP_MEMORY_SCOPE_AGENT);
        }
      }

      float acc0 = 0.f, acc1 = 0.f, acc2 = 0.f, acc3 = 0.f;
#pragma unroll
      for (int j = 0; j < 4; ++j) {
        floatx4 zv = *(const floatx4*)(cb + 256 * j + 4 * l);
        floatx4 w0 = wreg[0 * 4 + j], w1 = wreg[1 * 4 + j];
        floatx4 w2v = wreg[2 * 4 + j], w3 = wreg[3 * 4 + j];
        acc0 += w0.x * zv.x + w0.y * zv.y + w0.z * zv.z + w0.w * zv.w;
        acc1 += w1.x * zv.x + w1.y * zv.y + w1.z * zv.z + w1.w * zv.w;
        acc2 += w2v.x * zv.x + w2v.y * zv.y + w2v.z * zv.z + w2v.w * zv.w;
        acc3 += w3.x * zv.x + w3.y * zv.y + w3.z * zv.z + w3.w * zv.w;
      }
#pragma unroll
      for (int off = 1; off <= 32; off <<= 1) {
        acc0 += __shfl_xor(acc0, off, 64);
        acc1 += __shfl_xor(acc1, off, 64);
        acc2 += __shfl_xor(acc2, off, 64);
        acc3 += __shfl_xor(acc3, off, 64);
      }
      if (l == 0) {
        float y0 = acc0 * rs + blv[0], y1 = acc1 * rs + blv[1];
        float y2 = acc2 * rs + blv[2], y3 = acc3 * rs + blv[3];
        u64 a01 = ((u64)__builtin_bit_cast(unsigned, y1) << 32) |
                  (u64)__builtin_bit_cast(unsigned, y0);
        u64 a23 = ((u64)__builtin_bit_cast(unsigned, y3) << 32) |
                  (u64)__builtin_bit_cast(unsigned, y2);
        u64* dst = (u64*)(vbuf + ((size_t)i << 10) + r0);
        __hip_atomic_store(dst, a01, __ATOMIC_RELAXED,
                           __HIP_MEMORY_SCOPE_AGENT);
        __hip_atomic_store(dst + 1, a23, __ATOMIC_RELAXED,
                           __HIP_MEMORY_SCOPE_AGENT);
      }
    }

    // tail: ||y_63||^2 (publishes norm2[63] AFTER observing all of vbuf[63])
    if (blockIdx.x == 0 && (tid >> 6) == 0) {
      int l2 = tid & 63;
      const u64* src = (const u64*)(vbuf + ((size_t)(NSTEPS - 1) << 10)) + l2;
      u64 v[8];
      for (;;) {
        bool ok = true;
#pragma unroll
        for (int j = 0; j < 8; ++j) {
          v[j] = __hip_atomic_load(src + 64 * j, __ATOMIC_RELAXED,
                                   __HIP_MEMORY_SCOPE_AGENT);
          ok &= ((unsigned)(v[j] & 0xFFFFFFFFu) != 0xFFFFFFFFu) &
                ((unsigned)(v[j] >> 32) != 0xFFFFFFFFu);
        }
        if (__all(ok)) break;
        __builtin_amdgcn_s_sleep(1);
      }
      float sq = 0.f;
#pragma unroll
      for (int j = 0; j < 8; ++j) {
        float f0 = __builtin_bit_cast(float, (unsigned)(v[j] & 0xFFFFFFFFu));
        float f1 = __builtin_bit_cast(float, (unsigned)(v[j] >> 32));
        sq += f0 * f0 + f1 * f1;
      }
#pragma unroll
      for (int off = 1; off <= 32; off <<= 1) sq += __shfl_xor(sq, off, 64);
      if (l2 == 0) {
        unsigned nb = __builtin_bit_cast(unsigned, sq);
        __hip_atomic_store((unsigned*)(norm2 + (NSTEPS - 1)), nb,
                           __ATOMIC_RELAXED, __HIP_MEMORY_SCOPE_AGENT);
      }
    }
    __syncthreads();
  }
  // (non-recurrence blocks fall straight through to the GEMM queue)

  // ---------------- GEMM phase: all blocks, tile work-queue ----------------
  int half = tid >> 8, tid2 = tid & 255;
  _Float16* Ash = (_Float16*)(smem + half * 16384);
  _Float16* Bsh = Ash + 4096;
  unsigned* tslot = (unsigned*)(smem + 32768);
  float* nnsh = (float*)(smem + 32776);

  int lane = tid2 & 63, w2 = tid2 >> 6;
  int q = lane >> 4, m = lane & 15;
  int eoff = (w2 & 1) * 64, toff = (w2 >> 1) * 64;
  int ar = tid2 >> 1, as = (tid2 & 1) * 16;  // A staging: half a W row
  int bk = tid2 & 31, bt = (tid2 >> 5) * 16; // B staging: k-row, 16 t's

  for (;;) {
    if (tid == 0) {
      unsigned q0 = atomicAdd(gemmq, 2u);
      tslot[0] = q0;
      tslot[1] = q0 + 1u;
    }
    __syncthreads();
    if (tslot[0] >= NTILES) break;
    unsigned tau = tslot[half];
    int n = (int)(tau >> 5);
    int rem = (int)(tau & 31u);
    int e_base = (rem & 7) << 7, t_base = (rem >> 3) << 7;

    const float* Arow = W + ((size_t)(e_base + ar) << 10) + as;
    const float* Brow =
        h + ((size_t)n << 19) + ((size_t)bk << 9) + t_base + bt;

    floatx4 zero = {0.f, 0.f, 0.f, 0.f};
    floatx4 acc[4][4];
#pragma unroll
    for (int i = 0; i < 4; ++i)
#pragma unroll
      for (int j = 0; j < 4; ++j) acc[i][j] = zero;

    for (int k0 = 0; k0 < H2; k0 += 32) {
      // stage A: 16 fp32 -> 16 fp16, row-major [128][32]
      floatx4 a0 = *(const floatx4*)(Arow + k0);
      floatx4 a1 = *(const floatx4*)(Arow + k0 + 4);
      floatx4 a2 = *(const floatx4*)(Arow + k0 + 8);
      floatx4 a3 = *(const floatx4*)(Arow + k0 + 12);
      half8 h0, h1;
#pragma unroll
      for (int c = 0; c < 4; ++c) {
        h0[c] = (_Float16)a0[c];
        h0[4 + c] = (_Float16)a1[c];
        h1[c] = (_Float16)a2[c];
        h1[4 + c] = (_Float16)a3[c];
      }
      *(half8*)&Ash[ar * 32 + as] = h0;
      *(half8*)&Ash[ar * 32 + as + 8] = h1;

      // stage B: coalesced 64B read along t, scalar-write transpose to [t][k]
      floatx4 b0 = *(const floatx4*)(Brow + (size_t)k0 * TT);
      floatx4 b1 = *(const floatx4*)(Brow + (size_t)k0 * TT + 4);
      floatx4 b2 = *(const floatx4*)(Brow + (size_t)k0 * TT + 8);
      floatx4 b3 = *(const floatx4*)(Brow + (size_t)k0 * TT + 12);
#pragma unroll
      for (int c = 0; c < 4; ++c) {
        Bsh[(bt + c) * 32 + bk] = (_Float16)b0[c];
        Bsh[(bt + 4 + c) * 32 + bk] = (_Float16)b1[c];
        Bsh[(bt + 8 + c) * 32 + bk] = (_Float16)b2[c];
        Bsh[(bt + 12 + c) * 32 + bk] = (_Float16)b3[c];
      }
      __syncthreads();

      half8 af[4], bf[4];
#pragma unroll
      for (int i = 0; i < 4; ++i)
        af[i] = *(const half8*)&Ash[(eoff + i * 16 + m) * 32 + q * 8];
#pragma unroll
      for (int j = 0; j < 4; ++j)
        bf[j] = *(const half8*)&Bsh[(toff + j * 16 + m) * 32 + q * 8];
#pragma unroll
      for (int i = 0; i < 4; ++i)
#pragma unroll
        for (int j = 0; j < 4; ++j)
          acc[i][j] = __builtin_amdgcn_mfma_f32_16x16x32_f16(af[i], bf[j],
                                                             acc[i][j], 0, 0, 0);
      __syncthreads();
    }

    // epilogue: one thread spins on norm2[n]; vbuf then guaranteed visible
    float* uloc = (float*)Ash;
    float* bloc = uloc + 128;
    if (tid2 == 0) {
      for (;;) {
        unsigned b = __hip_atomic_load((const unsigned*)(norm2 + n),
                                       __ATOMIC_RELAXED,
                                       __HIP_MEMORY_SCOPE_AGENT);
        if (b != 0xFFFFFFFFu) {
          nnsh[half] = __builtin_bit_cast(float, b);
          break;
        }
        __builtin_amdgcn_s_sleep(4);
      }
    }
    __syncthreads();
    float rsn = 1.0f / fmaxf(sqrtf(nnsh[half]), 1e-12f);
    if (tid2 < 128) {
      unsigned b = __hip_atomic_load(
          (const unsigned*)(vbuf + ((size_t)n << 10) + e_base) + tid2,
          __ATOMIC_RELAXED, __HIP_MEMORY_SCOPE_AGENT);
      uloc[tid2] = __builtin_bit_cast(float, b) * rsn;
      bloc[tid2] = bias[e_base + tid2];
    }
    __syncthreads();

    float part[4] = {0.f, 0.f, 0.f, 0.f};
#pragma unroll
    for (int i = 0; i < 4; ++i) {
#pragma unroll
      for (int reg = 0; reg < 4; ++reg) {
        int el = eoff + i * 16 + q * 4 + reg;
        float ubv = uloc[el];
        float bbv = bloc[el];
#pragma unroll
        for (int j = 0; j < 4; ++j) {
          float y = acc[i][j][reg] + bbv;
          part[j] += tanh_fast(y) * ubv;
        }
      }
    }
#pragma unroll
    for (int j = 0; j < 4; ++j) {
      part[j] += __shfl_xor(part[j], 16, 64);
      part[j] += __shfl_xor(part[j], 32, 64);
      if (lane < 16) {
        int t = t_base + toff + j * 16 + lane;
        atomicAdd(&scores[(size_t)n * TT + t], part[j]);
      }
    }
    __syncthreads();  // drains score atomics across both halves
    if (tid2 == 0)
      __hip_atomic_fetch_add(donecnt + n, 1u, __ATOMIC_RELEASE,
                             __HIP_MEMORY_SCOPE_AGENT);
  }

  // ---------------- out phase: softmax + weighted sum, work-queue ----------
  {
    float* sa = (float*)smem;                  // 512
    float* red = sa + 512;                     // 16
    unsigned* oslot = (unsigned*)(sa + 528);
    int w = tid >> 6, lane2 = tid & 63;

    for (;;) {
      if (tid == 0) *oslot = atomicAdd(outq, 1u);
      __syncthreads();
      unsigned u = *oslot;
      __syncthreads();
      if (u >= NOUT) break;
      int n = (int)(u >> 3), dblk = (int)(u & 7u);

      if (tid == 0) {
        while (__hip_atomic_load(donecnt + n, __ATOMIC_ACQUIRE,
                                 __HIP_MEMORY_SCOPE_AGENT) < 32u)
          __builtin_amdgcn_s_sleep(1);
      }
      __syncthreads();

      float s = __builtin_bit_cast(
          float, __hip_atomic_load((const unsigned*)(scores + (size_t)n * TT) +
                                       tid,
                                   __ATOMIC_RELAXED, __HIP_MEMORY_SCOPE_AGENT));
      float mx = s;
#pragma unroll
      for (int off = 32; off >= 1; off >>= 1)
        mx = fmaxf(mx, __shfl_xor(mx, off, 64));
      if (lane2 == 0) red[w] = mx;
      __syncthreads();
      mx = red[0];
#pragma unroll
      for (int k2 = 1; k2 < 8; ++k2) mx = fmaxf(mx, red[k2]);
      float e = __expf(s - mx);
      float ssum = e;
#pragma unroll
      for (int off = 32; off >= 1; off >>= 1) ssum += __shfl_xor(ssum, off, 64);
      if (lane2 == 0) red[8 + w] = ssum;
      __syncthreads();
      ssum = 0.f;
#pragma unroll
      for (int k2 = 0; k2 < 8; ++k2) ssum += red[8 + k2];
      sa[tid] = e * (1.0f / ssum);
      __syncthreads();

      int d0 = dblk * 128 + w * 16;
      const float4* hb =
          reinterpret_cast<const float4*>(h + (size_t)n * H2 * TT);
#pragma unroll 1
      for (int rr = 0; rr < 16; ++rr) {
        int d = d0 + rr;
        const float4* hr = hb + (size_t)d * (TT / 4);
        float4 a4 = hr[lane2];
        float4 b4 = hr[64 + lane2];
        int t0 = 4 * lane2;
        float acc = a4.x * sa[t0] + a4.y * sa[t0 + 1] + a4.z * sa[t0 + 2] +
                    a4.w * sa[t0 + 3] + b4.x * sa[256 + t0] +
                    b4.y * sa[256 + t0 + 1] + b4.z * sa[256 + t0 + 2] +
                    b4.w * sa[256 + t0 + 3];
#pragma unroll
        for (int off = 1; off <= 32; off <<= 1) acc += __shfl_xor(acc, off, 64);
        if (lane2 == 0) out[(size_t)n * H2 + d] = acc;
      }
      __syncthreads();
    }
  }
}

// ---------------------------------------------------------------------------
extern "C" void kernel_launch(void* const* d_in, const int* in_sizes, int n_in,
                              void* d_out, int out_size, void* d_ws, size_t ws_size,
                              hipStream_t stream) {
  const float* h    = (const float*)d_in[0];  // (64, 1024, 512)
  const float* W    = (const float*)d_in[1];  // (1024, 1024)
  const float* bias = (const float*)d_in[2];  // (1024,)
  const float* u0   = (const float*)d_in[3];  // (1024,)
  float* out = (float*)d_out;                 // (64, 1024)

  // ws: [ 0xFF region: norm2(64f) vbuf(65536f) | zero region: scores(32768f)
  //       ctrs(128u) ]
  float* wsf    = (float*)d_ws;
  float* norm2  = wsf;                        // poisoned
  float* vbuf   = wsf + 64;                   // poisoned
  float* scores = wsf + 64 + (size_t)NSTEPS * H2;  // zeroed
  unsigned* ctrs = (unsigned*)(scores + (size_t)NSTEPS * TT);  // zeroed

  hipMemsetAsync(norm2, 0xFF, (64 + (size_t)NSTEPS * H2) * 4, stream);
  hipMemsetAsync(scores, 0, ((size_t)NSTEPS * TT + 128) * 4, stream);

  {
    const float* Wp = W; const float* bp = bias; const float* up = u0;
    float* vp = vbuf; float* np = norm2; const float* hp = h;
    float* sp = scores; float* op = out; unsigned* cp = ctrs;
    void* kargs[] = {&Wp, &bp, &up, &vp, &np, &hp, &sp, &op, &cp};
    hipLaunchCooperativeKernel((void*)fused_kernel, dim3(TOTBLK), dim3(RTHR),
                               kargs, 0, stream);
  }

  (void)in_sizes; (void)n_in; (void)out_size; (void)ws_size;
}

// Round 9
// 502.887 us; speedup vs baseline: 1.2680x; 1.2680x over previous
//
#include <hip/hip_runtime.h>
#include <cstdint>
#include <cstddef>

#define H2 1024
#define TT 512
#define NSTEPS 64
#define RBLK 32     // recurrence blocks
#define RTHR 512    // threads per block
#define PREBLK 224  // pre-pass worker blocks
#define TOTBLK 256
#define NTILES 2048u   // gemm tiles: 64 n * 8 e * 4 t (n-major)
#define NOUT 512u      // out units: 64 n * 8 dblk(128)

using floatx4 = __attribute__((__ext_vector_type__(4))) float;
using half8   = __attribute__((__ext_vector_type__(8))) _Float16;
using half4   = __attribute__((__ext_vector_type__(4))) _Float16;
typedef unsigned long long u64;

__device__ __forceinline__ float tanh_fast(float x) {
  return 1.0f - 2.0f / (__expf(2.0f * x) + 1.0f);
}

#define GLDS16(gp, lp)                                                         \
  __builtin_amdgcn_global_load_lds(                                            \
      (const __attribute__((address_space(1))) void*)(gp),                     \
      (__attribute__((address_space(3))) void*)(lp), 16, 0, 0)

// ---------------------------------------------------------------------------
// Consolidation of all proven pieces (R4 structure + R7 epilogue + R5 out):
//   blocks [0,32):   64-step recurrence (data-as-flag, single poller wave,
//                    W pinned in VGPRs) -> gemm queue -> out queue.
//   blocks [32,256): wconv + transpose_h (agent-scope stores for cross-XCD
//                    visibility), release `done` -> gemm queue -> out queue.
// GEMM: R4's exact 2-barrier gload_lds K-loop (no swizzle, no sw pipeline —
// both measured regressions in R5). Epilogue: 1-thread spin on norm2[n]
// (published only after block 0 OBSERVED all vbuf[n] at LLC, so subsequent
// plain agent loads of vbuf are guaranteed fresh), then tanh + u_ws dot ->
// scores atomics -> donecnt[n]++.
// Out phase (in-kernel, overlaps recur tail): per-n gate donecnt[n]==32,
// softmax + weighted sum h·a -> out.
// ---------------------------------------------------------------------------
__global__ __launch_bounds__(RTHR, 1) void fused_kernel(
    const float* __restrict__ W, const float* __restrict__ bias,
    const float* __restrict__ u0, float* __restrict__ vbuf,
    float* __restrict__ norm2, _Float16* __restrict__ Wh,
    const float* __restrict__ h, _Float16* __restrict__ hhT,
    float* __restrict__ scores, float* __restrict__ out,
    unsigned* __restrict__ ctrs) {
  __shared__ __align__(16) char smem[33792];
  int tid = threadIdx.x;
  unsigned* done    = ctrs;        // prepass completion count
  unsigned* gemmq   = ctrs + 16;   // gemm tile queue
  unsigned* donecnt = ctrs + 32;   // per-n completed tiles (64)
  unsigned* outq    = ctrs + 96;   // out-unit queue

  if (blockIdx.x < RBLK) {
    // ------------------------- recurrence role ---------------------------
    float* ub = (float*)smem;              // [2][1024] double-buffered z
    float* bredn = (float*)(smem + 8192);  // [2] norm^2
    int w = tid >> 6, l = tid & 63;
    int r0 = blockIdx.x * RBLK + w * 4;

    floatx4 wreg[16];
    float blv[4];
#pragma unroll
    for (int p = 0; p < 4; ++p) {
      const float* wr = W + ((size_t)(r0 + p) << 10) + 4 * l;
#pragma unroll
      for (int j = 0; j < 4; ++j)
        wreg[p * 4 + j] = *(const floatx4*)(wr + 256 * j);
      blv[p] = bias[r0 + p];
    }
#pragma unroll
    for (int j = 0; j < 16; ++j) asm volatile("" : "+v"(wreg[j]));

    for (int i = 0; i < NSTEPS; ++i) {
      float* cb = ub + (i & 1) * 1024;
      float rs;
      if (i == 0) {
        if (w == 0) {
#pragma unroll
          for (int j = 0; j < 4; ++j) {
            floatx4 v = *((const floatx4*)u0 + l + 64 * j);
            *(floatx4*)(cb + 4 * l + 256 * j) = v;
          }
        }
        __syncthreads();
        rs = 1.0f;
      } else {
        if (w == 0) {
          const u64* src = (const u64*)(vbuf + ((size_t)(i - 1) << 10)) + l;
          u64 v[8];
          for (;;) {
            bool ok = true;
#pragma unroll
            for (int j = 0; j < 8; ++j) {
              v[j] = __hip_atomic_load(src + 64 * j, __ATOMIC_RELAXED,
                                       __HIP_MEMORY_SCOPE_AGENT);
              ok &= ((unsigned)(v[j] & 0xFFFFFFFFu) != 0xFFFFFFFFu) &
                    ((unsigned)(v[j] >> 32) != 0xFFFFFFFFu);
            }
            if (__all(ok)) break;
            __builtin_amdgcn_s_sleep(1);
          }
          float sq = 0.f;
#pragma unroll
          for (int j = 0; j < 8; ++j) {
            *(u64*)(cb + 2 * l + 128 * j) = v[j];
            float f0 =
                __builtin_bit_cast(float, (unsigned)(v[j] & 0xFFFFFFFFu));
            float f1 = __builtin_bit_cast(float, (unsigned)(v[j] >> 32));
            sq += f0 * f0 + f1 * f1;
          }
#pragma unroll
          for (int off = 1; off <= 32; off <<= 1)
            sq += __shfl_xor(sq, off, 64);
          if (l == 0) bredn[i & 1] = sq;
        }
        __syncthreads();
        float nrm = bredn[i & 1];
        rs = 1.0f / fmaxf(sqrtf(nrm), 1e-12f);
        if (blockIdx.x == 0 && tid == 64) {
          unsigned nb = __builtin_bit_cast(unsigned, nrm);
          __hip_atomic_store((unsigned*)(norm2 + (i - 1)), nb,
                             __ATOMIC_RELAXED, __HIP_MEMORY_SCOPE_AGENT);
        }
      }

      float acc0 = 0.f, acc1 = 0.f, acc2 = 0.f, acc3 = 0.f;
#pragma unroll
      for (int j = 0; j < 4; ++j) {
        floatx4 zv = *(const floatx4*)(cb + 256 * j + 4 * l);
        floatx4 w0 = wreg[0 * 4 + j], w1 = wreg[1 * 4 + j];
        floatx4 w2v = wreg[2 * 4 + j], w3 = wreg[3 * 4 + j];
        acc0 += w0.x * zv.x + w0.y * zv.y + w0.z * zv.z + w0.w * zv.w;
        acc1 += w1.x * zv.x + w1.y * zv.y + w1.z * zv.z + w1.w * zv.w;
        acc2 += w2v.x * zv.x + w2v.y * zv.y + w2v.z * zv.z + w2v.w * zv.w;
        acc3 += w3.x * zv.x + w3.y * zv.y + w3.z * zv.z + w3.w * zv.w;
      }
#pragma unroll
      for (int off = 1; off <= 32; off <<= 1) {
        acc0 += __shfl_xor(acc0, off, 64);
        acc1 += __shfl_xor(acc1, off, 64);
        acc2 += __shfl_xor(acc2, off, 64);
        acc3 += __shfl_xor(acc3, off, 64);
      }
      if (l == 0) {
        float y0 = acc0 * rs + blv[0], y1 = acc1 * rs + blv[1];
        float y2 = acc2 * rs + blv[2], y3 = acc3 * rs + blv[3];
        u64 a01 = ((u64)__builtin_bit_cast(unsigned, y1) << 32) |
                  (u64)__builtin_bit_cast(unsigned, y0);
        u64 a23 = ((u64)__builtin_bit_cast(unsigned, y3) << 32) |
                  (u64)__builtin_bit_cast(unsigned, y2);
        u64* dst = (u64*)(vbuf + ((size_t)i << 10) + r0);
        __hip_atomic_store(dst, a01, __ATOMIC_RELAXED,
                           __HIP_MEMORY_SCOPE_AGENT);
        __hip_atomic_store(dst + 1, a23, __ATOMIC_RELAXED,
                           __HIP_MEMORY_SCOPE_AGENT);
      }
    }

    // tail: ||y_63||^2 (published only after observing all vbuf[63] at LLC)
    if (blockIdx.x == 0 && (tid >> 6) == 0) {
      int l2 = tid & 63;
      const u64* src = (const u64*)(vbuf + ((size_t)(NSTEPS - 1) << 10)) + l2;
      u64 v[8];
      for (;;) {
        bool ok = true;
#pragma unroll
        for (int j = 0; j < 8; ++j) {
          v[j] = __hip_atomic_load(src + 64 * j, __ATOMIC_RELAXED,
                                   __HIP_MEMORY_SCOPE_AGENT);
          ok &= ((unsigned)(v[j] & 0xFFFFFFFFu) != 0xFFFFFFFFu) &
                ((unsigned)(v[j] >> 32) != 0xFFFFFFFFu);
        }
        if (__all(ok)) break;
        __builtin_amdgcn_s_sleep(1);
      }
      float sq = 0.f;
#pragma unroll
      for (int j = 0; j < 8; ++j) {
        float f0 = __builtin_bit_cast(float, (unsigned)(v[j] & 0xFFFFFFFFu));
        float f1 = __builtin_bit_cast(float, (unsigned)(v[j] >> 32));
        sq += f0 * f0 + f1 * f1;
      }
#pragma unroll
      for (int off = 1; off <= 32; off <<= 1) sq += __shfl_xor(sq, off, 64);
      if (l2 == 0) {
        unsigned nb = __builtin_bit_cast(unsigned, sq);
        __hip_atomic_store((unsigned*)(norm2 + (NSTEPS - 1)), nb,
                           __ATOMIC_RELAXED, __HIP_MEMORY_SCOPE_AGENT);
      }
    }
    __syncthreads();
  } else {
    // ------------------- pre-pass role (overlapped) ----------------------
    int pb = blockIdx.x - RBLK;  // 0..223

    const floatx4* Wv = (const floatx4*)W;
    for (int idx = pb * RTHR + tid; idx < H2 * H2 / 4; idx += PREBLK * RTHR) {
      floatx4 v = Wv[idx];
      half4 o = {(_Float16)v.x, (_Float16)v.y, (_Float16)v.z, (_Float16)v.w};
      __hip_atomic_store((u64*)Wh + idx, __builtin_bit_cast(u64, o),
                         __ATOMIC_RELAXED, __HIP_MEMORY_SCOPE_AGENT);
    }

    int sub = tid >> 8, ltid = tid & 255;
    float(*tile)[65] = (float(*)[65])(smem + sub * 16640);
    int dr = ltid >> 4, tc = (ltid & 15) << 2;
    int tr = ltid >> 3, seg = ltid & 7;
    for (int base = pb * 2; base < 8192; base += PREBLK * 2) {
      int tidx = base + sub;
      bool act = tidx < 8192;
      int n = tidx >> 7, rem = tidx & 127;
      int d0 = (rem & 15) << 6, t0 = ((rem >> 4) & 7) << 6;
      if (act) {
        const float* hb = h + ((size_t)n * H2 + d0) * TT + t0;
#pragma unroll
        for (int p = 0; p < 4; ++p) {
          floatx4 v = *(const floatx4*)(hb + (size_t)(dr + p * 16) * TT + tc);
          tile[dr + p * 16][tc] = v.x;
          tile[dr + p * 16][tc + 1] = v.y;
          tile[dr + p * 16][tc + 2] = v.z;
          tile[dr + p * 16][tc + 3] = v.w;
        }
      }
      __syncthreads();
      if (act) {
        _Float16* ob = hhT + ((size_t)n * TT + t0) * H2 + d0;
#pragma unroll
        for (int p = 0; p < 2; ++p) {
          int t = tr + p * 32;
          union { half8 v; u64 u[2]; } hu;
#pragma unroll
          for (int u = 0; u < 8; ++u) hu.v[u] = (_Float16)tile[seg * 8 + u][t];
          u64* op = (u64*)(ob + (size_t)t * H2 + seg * 8);
          __hip_atomic_store(op, hu.u[0], __ATOMIC_RELAXED,
                             __HIP_MEMORY_SCOPE_AGENT);
          __hip_atomic_store(op + 1, hu.u[1], __ATOMIC_RELAXED,
                             __HIP_MEMORY_SCOPE_AGENT);
        }
      }
      __syncthreads();
    }
    asm volatile("s_waitcnt vmcnt(0)" ::: "memory");
    __syncthreads();
    if (tid == 0)
      __hip_atomic_fetch_add(done, 1u, __ATOMIC_RELEASE,
                             __HIP_MEMORY_SCOPE_AGENT);
  }

  // ---------------- GEMM phase: all blocks, tile work-queue ----------------
  if (tid == 0) {
    while (__hip_atomic_load(done, __ATOMIC_ACQUIRE,
                             __HIP_MEMORY_SCOPE_AGENT) < (unsigned)PREBLK)
      __builtin_amdgcn_s_sleep(2);
  }
  __syncthreads();

  int half = tid >> 8, tid2 = tid & 255;
  _Float16* Ash = (_Float16*)(smem + half * 16384);
  _Float16* Bsh = Ash + 4096;
  unsigned* tslot = (unsigned*)(smem + 33288);
  float* nnsh = (float*)(smem + 33296);

  int lane = tid2 & 63, w2 = tid2 >> 6;
  int q = lane >> 4, m = lane & 15;
  int eoff = (w2 & 1) * 64, toff = (w2 >> 1) * 64;
  int rl = lane >> 2, kseg = lane & 3;
  _Float16* lA0 = Ash + (w2 * 32) * 32;
  _Float16* lA1 = lA0 + 16 * 32;
  _Float16* lB0 = Bsh + (w2 * 32) * 32;
  _Float16* lB1 = lB0 + 16 * 32;

  for (;;) {
    if (tid == 0) {
      unsigned q0 = atomicAdd(gemmq, 2u);
      tslot[0] = q0;
      tslot[1] = q0 + 1u;
    }
    __syncthreads();
    if (tslot[0] >= NTILES) break;
    unsigned tau = tslot[half];
    int n = (int)(tau >> 5);
    int rem = (int)(tau & 31u);
    int e_base = (rem & 7) << 7, t_base = (rem >> 3) << 7;

    const _Float16* gA0 =
        Wh + (((size_t)(e_base + w2 * 32 + rl)) << 10) + kseg * 8;
    const _Float16* gA1 = gA0 + ((size_t)16 << 10);
    const _Float16* gB0 = hhT + ((size_t)n << 19) +
                          (((size_t)(t_base + w2 * 32 + rl)) << 10) + kseg * 8;
    const _Float16* gB1 = gB0 + ((size_t)16 << 10);

    floatx4 zero = {0.f, 0.f, 0.f, 0.f};
    floatx4 acc[4][4];
#pragma unroll
    for (int i = 0; i < 4; ++i)
#pragma unroll
      for (int j = 0; j < 4; ++j) acc[i][j] = zero;

    for (int k0 = 0; k0 < H2; k0 += 32) {
      GLDS16(gA0 + k0, lA0);
      GLDS16(gA1 + k0, lA1);
      GLDS16(gB0 + k0, lB0);
      GLDS16(gB1 + k0, lB1);
      __syncthreads();

      half8 af[4], bf[4];
#pragma unroll
      for (int i = 0; i < 4; ++i)
        af[i] = *(const half8*)&Ash[(eoff + i * 16 + m) * 32 + q * 8];
#pragma unroll
      for (int j = 0; j < 4; ++j)
        bf[j] = *(const half8*)&Bsh[(toff + j * 16 + m) * 32 + q * 8];
#pragma unroll
      for (int i = 0; i < 4; ++i)
#pragma unroll
        for (int j = 0; j < 4; ++j)
          acc[i][j] = __builtin_amdgcn_mfma_f32_16x16x32_f16(af[i], bf[j],
                                                             acc[i][j], 0, 0, 0);
      __syncthreads();
    }

    // epilogue: 1-thread spin on norm2[n]; vbuf then guaranteed LLC-visible
    float* uloc = (float*)Ash;
    float* bloc = uloc + 128;
    if (tid2 == 0) {
      for (;;) {
        unsigned b = __hip_atomic_load((const unsigned*)(norm2 + n),
                                       __ATOMIC_RELAXED,
                                       __HIP_MEMORY_SCOPE_AGENT);
        if (b != 0xFFFFFFFFu) {
          nnsh[half] = __builtin_bit_cast(float, b);
          break;
        }
        __builtin_amdgcn_s_sleep(4);
      }
    }
    __syncthreads();
    float rsn = 1.0f / fmaxf(sqrtf(nnsh[half]), 1e-12f);
    if (tid2 < 128) {
      unsigned b = __hip_atomic_load(
          (const unsigned*)(vbuf + ((size_t)n << 10) + e_base) + tid2,
          __ATOMIC_RELAXED, __HIP_MEMORY_SCOPE_AGENT);
      uloc[tid2] = __builtin_bit_cast(float, b) * rsn;
      bloc[tid2] = bias[e_base + tid2];
    }
    __syncthreads();

    float part[4] = {0.f, 0.f, 0.f, 0.f};
#pragma unroll
    for (int i = 0; i < 4; ++i) {
#pragma unroll
      for (int reg = 0; reg < 4; ++reg) {
        int el = eoff + i * 16 + q * 4 + reg;
        float ubv = uloc[el];
        float bbv = bloc[el];
#pragma unroll
        for (int j = 0; j < 4; ++j) {
          float y = acc[i][j][reg] + bbv;
          part[j] += tanh_fast(y) * ubv;
        }
      }
    }
#pragma unroll
    for (int j = 0; j < 4; ++j) {
      part[j] += __shfl_xor(part[j], 16, 64);
      part[j] += __shfl_xor(part[j], 32, 64);
      if (lane < 16) {
        int t = t_base + toff + j * 16 + lane;
        atomicAdd(&scores[(size_t)n * TT + t], part[j]);
      }
    }
    __syncthreads();  // drains score atomics across both halves
    if (tid2 == 0)
      __hip_atomic_fetch_add(donecnt + n, 1u, __ATOMIC_RELEASE,
                             __HIP_MEMORY_SCOPE_AGENT);
  }

  // ---------------- out phase: softmax + weighted sum, work-queue ----------
  {
    float* sa = (float*)smem;                  // 512
    float* red = sa + 512;                     // 16
    unsigned* oslot = (unsigned*)(sa + 528);
    int w = tid >> 6, lane2 = tid & 63;

    for (;;) {
      if (tid == 0) *oslot = atomicAdd(outq, 1u);
      __syncthreads();
      unsigned u = *oslot;
      __syncthreads();
      if (u >= NOUT) break;
      int n = (int)(u >> 3), dblk = (int)(u & 7u);

      if (tid == 0) {
        while (__hip_atomic_load(donecnt + n, __ATOMIC_ACQUIRE,
                                 __HIP_MEMORY_SCOPE_AGENT) < 32u)
          __builtin_amdgcn_s_sleep(1);
      }
      __syncthreads();

      float s = __builtin_bit_cast(
          float, __hip_atomic_load((const unsigned*)(scores + (size_t)n * TT) +
                                       tid,
                                   __ATOMIC_RELAXED, __HIP_MEMORY_SCOPE_AGENT));
      float mx = s;
#pragma unroll
      for (int off = 32; off >= 1; off >>= 1)
        mx = fmaxf(mx, __shfl_xor(mx, off, 64));
      if (lane2 == 0) red[w] = mx;
      __syncthreads();
      mx = red[0];
#pragma unroll
      for (int k2 = 1; k2 < 8; ++k2) mx = fmaxf(mx, red[k2]);
      float e = __expf(s - mx);
      float ssum = e;
#pragma unroll
      for (int off = 32; off >= 1; off >>= 1) ssum += __shfl_xor(ssum, off, 64);
      if (lane2 == 0) red[8 + w] = ssum;
      __syncthreads();
      ssum = 0.f;
#pragma unroll
      for (int k2 = 0; k2 < 8; ++k2) ssum += red[8 + k2];
      sa[tid] = e * (1.0f / ssum);
      __syncthreads();

      int d0 = dblk * 128 + w * 16;
      const float4* hb =
          reinterpret_cast<const float4*>(h + (size_t)n * H2 * TT);
#pragma unroll 1
      for (int rr = 0; rr < 16; ++rr) {
        int d = d0 + rr;
        const float4* hr = hb + (size_t)d * (TT / 4);
        float4 a4 = hr[lane2];
        float4 b4 = hr[64 + lane2];
        int t0 = 4 * lane2;
        float acc = a4.x * sa[t0] + a4.y * sa[t0 + 1] + a4.z * sa[t0 + 2] +
                    a4.w * sa[t0 + 3] + b4.x * sa[256 + t0] +
                    b4.y * sa[256 + t0 + 1] + b4.z * sa[256 + t0 + 2] +
                    b4.w * sa[256 + t0 + 3];
#pragma unroll
        for (int off = 1; off <= 32; off <<= 1) acc += __shfl_xor(acc, off, 64);
        if (lane2 == 0) out[(size_t)n * H2 + d] = acc;
      }
      __syncthreads();
    }
  }
}

// ---------------------------------------------------------------------------
extern "C" void kernel_launch(void* const* d_in, const int* in_sizes, int n_in,
                              void* d_out, int out_size, void* d_ws, size_t ws_size,
                              hipStream_t stream) {
  const float* h    = (const float*)d_in[0];  // (64, 1024, 512)
  const float* W    = (const float*)d_in[1];  // (1024, 1024)
  const float* bias = (const float*)d_in[2];  // (1024,)
  const float* u0   = (const float*)d_in[3];  // (1024,)
  float* out = (float*)d_out;                 // (64, 1024)

  // ws: [ 0xFF: norm2(64f) vbuf(65536f) | zero: scores(32768f) ctrs(128u) |
  //       Wh(1M halfs) | hhT(32M halfs) ]
  float* wsf    = (float*)d_ws;
  float* norm2  = wsf;                              // poisoned
  float* vbuf   = wsf + 64;                         // poisoned
  float* scores = wsf + 64 + (size_t)NSTEPS * H2;   // zeroed
  unsigned* ctrs = (unsigned*)(scores + (size_t)NSTEPS * TT);  // zeroed
  _Float16* Wh  = (_Float16*)(ctrs + 128);          // 1M halfs
  _Float16* hhT = Wh + (size_t)H2 * H2;             // 32M halfs

  hipMemsetAsync(norm2, 0xFF, (64 + (size_t)NSTEPS * H2) * 4, stream);
  hipMemsetAsync(scores, 0, ((size_t)NSTEPS * TT + 128) * 4, stream);

  {
    const float* Wp = W; const float* bp = bias; const float* up = u0;
    float* vp = vbuf; float* np = norm2;
    _Float16* whp = Wh; const float* hp = h; _Float16* htp = hhT;
    float* sp = scores; float* op = out; unsigned* cp = ctrs;
    void* kargs[] = {&Wp, &bp, &up, &vp, &np, &whp, &hp, &htp, &sp, &op, &cp};
    hipLaunchCooperativeKernel((void*)fused_kernel, dim3(TOTBLK), dim3(RTHR),
                               kargs, 0, stream);
  }

  (void)in_sizes; (void)n_in; (void)out_size; (void)ws_size;
}